// Round 1
// baseline (55.715 us; speedup 1.0000x reference)
//
#include <hip/hip_runtime.h>
#include <math.h>

// BSplineActivation: y = sum_j B_j^3(x) * w_j over uniform knots
// linspace(-pi, pi, 1024), degree 3 -> 1020 basis funcs / weights.
// Closed form: at most 4 nonzero cubic basis values per point.

#define NW   1020   // number of weights / degree-3 basis functions
#define NI   1023   // number of knot intervals (len(knots)-1)

__global__ __launch_bounds__(256) void bspline_act_kernel(
    const float* __restrict__ x,
    const float* __restrict__ w,
    float* __restrict__ out,
    int n)
{
    __shared__ float ws[NW];
    const int t = threadIdx.x;
    // Stage the 1020 weights into LDS: 255 float4 loads (threads 0..254).
    if (t < NW / 4) {
        reinterpret_cast<float4*>(ws)[t] = reinterpret_cast<const float4*>(w)[t];
    }
    __syncthreads();

    const float T0    = (float)(-3.14159265358979323846);        // knots[0]
    const float INV_H = (float)(1023.0 / (2.0 * 3.14159265358979323846));

    const int base = (blockIdx.x * 256 + t) * 4;
    if (base >= n) return;  // n is a multiple of 4 (262144)

    const float4 xv = *reinterpret_cast<const float4*>(x + base);
    float xs[4] = {xv.x, xv.y, xv.z, xv.w};
    float r[4];

#pragma unroll
    for (int e = 0; e < 4; ++e) {
        const float s  = (xs[e] - T0) * INV_H;
        const float sf = floorf(s);
        const int   i  = (int)sf;
        float o = 0.0f;
        if (i >= 0 && i < NI) {                 // x inside [knots[0], knots[1023])
            const float u  = s - sf;            // local coordinate in [0,1)
            const float um = 1.0f - u;
            const float u2 = u * u;
            const float u3 = u2 * u;
            // Uniform cubic B-spline basis (verified vs Cox-de Boor):
            const float b0 = um * um * um * (1.0f / 6.0f);
            const float b1 = (3.0f * u3 - 6.0f * u2 + 4.0f) * (1.0f / 6.0f);
            const float b2 = (-3.0f * u3 + 3.0f * u2 + 3.0f * u + 1.0f) * (1.0f / 6.0f);
            const float b3 = u3 * (1.0f / 6.0f);
            const int j = i - 3;                // first contributing weight index
            // Truncate basis indices falling outside [0, NW) (grid edges).
            o  = (j     >= 0 && j     < NW) ? b0 * ws[j]     : 0.0f;
            o += (j + 1 >= 0 && j + 1 < NW) ? b1 * ws[j + 1] : 0.0f;
            o += (j + 2 >= 0 && j + 2 < NW) ? b2 * ws[j + 2] : 0.0f;
            o += (j + 3 >= 0 && j + 3 < NW) ? b3 * ws[j + 3] : 0.0f;
        }
        r[e] = o;
    }

    *reinterpret_cast<float4*>(out + base) = make_float4(r[0], r[1], r[2], r[3]);
}

extern "C" void kernel_launch(void* const* d_in, const int* in_sizes, int n_in,
                              void* d_out, int out_size, void* d_ws, size_t ws_size,
                              hipStream_t stream)
{
    const float* x = (const float*)d_in[0];   // [N] points
    const float* w = (const float*)d_in[1];   // [1020] weights
    float* out = (float*)d_out;               // [N]
    const int n = in_sizes[0];

    const int threads = 256;
    const int blocks  = (n / 4 + threads - 1) / threads;   // 256 for N=262144
    bspline_act_kernel<<<blocks, threads, 0, stream>>>(x, w, out, n);
}

// Round 2
// 55.391 us; speedup vs baseline: 1.0059x; 1.0059x over previous
//
#include <hip/hip_runtime.h>
#include <math.h>

// BSplineActivation: y = sum_j B_j^3(x) * w_j, uniform knots linspace(-pi,pi,1024),
// degree 3 -> 1020 weights. Closed form: exactly 4 nonzero cubic basis values per
// point; interval i = floor((x-t0)/h), local u in [0,1).
//
// LDS weight table is zero-padded on both sides (ws[0..3]=0, ws[4..1023]=weights,
// ws[1024..1027]=0) so the 4 taps need no bounds checks: tap m reads ws[i+1+m],
// and edge-truncated basis indices land in the zero pads (same result as the
// predicated version, branch-free).

#define NW 1020   // number of weights / basis functions
#define NI 1023   // number of knot intervals

__global__ __launch_bounds__(256) void bspline_act_kernel(
    const float* __restrict__ x,
    const float* __restrict__ w,
    float* __restrict__ out,
    int n)
{
    __shared__ float ws[1028];           // 4 zero | 1020 weights | 4 zero
    const int t = threadIdx.x;
    float4* ws4 = reinterpret_cast<float4*>(ws);
    if (t < NW / 4) {                    // threads 0..254 stage the weights
        ws4[t + 1] = reinterpret_cast<const float4*>(w)[t];
    }
    if (t == 255) {                      // zero the pads
        ws4[0]   = make_float4(0.f, 0.f, 0.f, 0.f);
        ws4[256] = make_float4(0.f, 0.f, 0.f, 0.f);
    }
    __syncthreads();

    const float T0    = (float)(-3.14159265358979323846);
    const float INV_H = (float)(1023.0 / (2.0 * 3.14159265358979323846));

    const int base = (blockIdx.x * 256 + t) * 4;
    if (base >= n) return;               // n = 262144, multiple of 4

    const float4 xv = *reinterpret_cast<const float4*>(x + base);
    float xs[4] = {xv.x, xv.y, xv.z, xv.w};
    float r[4];

#pragma unroll
    for (int e = 0; e < 4; ++e) {
        const float s  = (xs[e] - T0) * INV_H;
        const float sf = floorf(s);
        const int   i  = (int)sf;
        float o = 0.0f;
        if (i >= 0 && i < NI) {          // x inside [knots[0], knots[1023])
            const float u  = s - sf;
            const float um = 1.0f - u;
            const float u2 = u * u;
            const float u3 = u2 * u;
            const float b0 = um * um * um * (1.0f / 6.0f);
            const float b1 = ( 3.0f * u3 - 6.0f * u2 + 4.0f) * (1.0f / 6.0f);
            const float b2 = (-3.0f * u3 + 3.0f * u2 + 3.0f * u + 1.0f) * (1.0f / 6.0f);
            const float b3 = u3 * (1.0f / 6.0f);
            const float* p = &ws[i + 1]; // taps: weights i-3 .. i (zero-padded)
            o = fmaf(b0, p[0], fmaf(b1, p[1], fmaf(b2, p[2], b3 * p[3])));
        }
        r[e] = o;
    }

    *reinterpret_cast<float4*>(out + base) = make_float4(r[0], r[1], r[2], r[3]);
}

extern "C" void kernel_launch(void* const* d_in, const int* in_sizes, int n_in,
                              void* d_out, int out_size, void* d_ws, size_t ws_size,
                              hipStream_t stream)
{
    const float* x = (const float*)d_in[0];   // [N]
    const float* w = (const float*)d_in[1];   // [1020]
    float* out = (float*)d_out;               // [N]
    const int n = in_sizes[0];

    const int threads = 256;
    const int blocks  = (n / 4 + threads - 1) / threads;   // 256 for N=262144
    bspline_act_kernel<<<blocks, threads, 0, stream>>>(x, w, out, n);
}